// Round 4
// baseline (53.369 us; speedup 1.0000x reference)
//
#include <hip/hip_runtime.h>
#include <math.h>

#define D      2048
#define KSEL   256
#define NT     256          // threads per row; block = 2 rows = 512
#define NBINS  256

typedef float f2 __attribute__((ext_vector_type(2)));
typedef float f4 __attribute__((ext_vector_type(4)));

// ws layout: [0:D) a = 32/std ; [D:2D) b = -32*mean/std ;
//            [2D:3D) u = ema_out/(||ema_out||+1e-8) ; [3D:3D+3) tau,sigma,w
__global__ __launch_bounds__(NT) void prep_kernel(
    const float* __restrict__ ema_mean,
    const float* __restrict__ ema_sq,
    const float* __restrict__ ema_out,
    const float* __restrict__ p_log_tau,
    const float* __restrict__ p_log_sigma,
    const float* __restrict__ p_log_w,
    float* __restrict__ ws)
{
    __shared__ float red[4];
    const int tid = threadIdx.x;
    float ss = 0.f;
#pragma unroll
    for (int k = 0; k < D / NT; ++k) {
        int i = tid + k * NT;
        float m = ema_mean[i];
        float v = fmaxf(fmaf(-m, m, ema_sq[i]), 1e-6f);
        float inv = 32.0f * __builtin_amdgcn_rsqf(v);   // 32/std
        ws[i]     = inv;
        ws[D + i] = -m * inv;
        float e = ema_out[i];
        ss = fmaf(e, e, ss);
    }
#pragma unroll
    for (int o = 32; o > 0; o >>= 1) ss += __shfl_down(ss, o, 64);
    if ((tid & 63) == 0) red[tid >> 6] = ss;
    __syncthreads();
    float inv_nrm = 1.0f / (sqrtf(red[0] + red[1] + red[2] + red[3]) + 1e-8f);
#pragma unroll
    for (int k = 0; k < D / NT; ++k) {
        int i = tid + k * NT;
        ws[2 * D + i] = ema_out[i] * inv_nrm;
    }
    if (tid == 0) {
        ws[3 * D + 0] = __expf(p_log_tau[0]);
        ws[3 * D + 1] = __logf(1.0f + __expf(p_log_sigma[0])) + 0.01f;
        ws[3 * D + 2] = __logf(1.0f + __expf(p_log_w[0]));
    }
}

// 512 threads = 2 rows per block; threads [0,256) -> row 2b, [256,512) -> row 2b+1
__global__ __launch_bounds__(512) void row_kernel(
    const float* __restrict__ x,
    const float* __restrict__ ws,
    float* __restrict__ out)
{
    __shared__ int   hist[2][NBINS];
    __shared__ int   wsum[2][4];
    __shared__ float red[2][4][3];
    __shared__ int   bsel_sh[2], krem_sh[2];

    const int tid  = threadIdx.x;
    const int half = tid >> 8;
    const int t    = tid & (NT - 1);
    const size_t rowoff = ((size_t)blockIdx.x * 2 + half) * (size_t)D;
    const float* __restrict__ xr = x + rowoff;

    hist[half][t] = 0;

    const float tau   = ws[3 * D + 0];
    const float sigma = ws[3 * D + 1];
    const float w     = ws[3 * D + 2];

    f4 xa = ((const f4*)xr)[t];
    f4 xb = ((const f4*)xr)[t + NT];
    f4 aa = ((const f4*)ws)[t];
    f4 ab = ((const f4*)ws)[t + NT];
    f4 ba = ((const f4*)(ws + D))[t];
    f4 bb = ((const f4*)(ws + D))[t + NT];
    f4 ua = ((const f4*)(ws + 2 * D))[t];
    f4 ub = ((const f4*)(ws + 2 * D))[t + NT];

    f2 xp[4] = {xa.lo, xa.hi, xb.lo, xb.hi};
    f2 ap[4] = {aa.lo, aa.hi, bb.lo, bb.hi};   // placeholder fixed below
    ap[0] = aa.lo; ap[1] = aa.hi; ap[2] = ab.lo; ap[3] = ab.hi;
    f2 bp[4] = {ba.lo, ba.hi, bb.lo, bb.hi};
    f2 up[4] = {ua.lo, ua.hi, ub.lo, ub.hi};

    f2 g[4];
    float av[8];                       // signed 32*z; abs applied at consumers
    f2 dot2 = (f2)0.f, nrm2 = (f2)0.f;
#pragma unroll
    for (int p = 0; p < 4; ++p) {
        f2 zv = xp[p] * ap[p] + bp[p];              // pk_fma: 32*z
        av[2 * p]     = zv.x;
        av[2 * p + 1] = zv.y;
        f2 x2 = xp[p] * xp[p];                      // pk_mul
        f2 tt = x2 * (-0.0713548162f) + (-1.5957691216f);  // pk_fma
        f2 ar = xp[p] * tt;                         // pk_mul
        f2 e;
        e.x = __expf(ar.x);
        e.y = __expf(ar.y);
        f2 den = e + 1.0f;                          // pk_add
        f2 r;
        r.x = __builtin_amdgcn_rcpf(den.x);
        r.y = __builtin_amdgcn_rcpf(den.y);
        f2 gg = xp[p] * r;                          // pk_mul: gelu(x)
        g[p] = gg;
        dot2 = gg * up[p] + dot2;                   // pk_fma
        nrm2 = gg * gg + nrm2;                      // pk_fma
    }

    __syncthreads();   // hist zeros visible
#pragma unroll
    for (int j = 0; j < 8; ++j) {
        int b = (int)fminf(fabsf(av[j]), 255.0f);   // abs = src modifier
        atomicAdd(&hist[half][b], 1);
    }
    __syncthreads();

    // suffix scan from the top bin (per half): boundary bin for K-th largest
    {
        int bin = (NBINS - 1) - t;
        int h = hist[half][bin];
        int p = h;
#pragma unroll
        for (int o = 1; o < 64; o <<= 1) {
            int q = __shfl_up(p, o, 64);
            if ((t & 63) >= o) p += q;
        }
        if ((t & 63) == 63) wsum[half][t >> 6] = p;
        __syncthreads();
        int off = 0;
        for (int wv = 0; wv < (t >> 6); ++wv) off += wsum[half][wv];
        int suf_incl = p + off;
        int suf_excl = suf_incl - h;
        if (suf_excl < KSEL && suf_incl >= KSEL) {
            bsel_sh[half] = bin;
            krem_sh[half] = KSEL - suf_excl;
        }
    }
    __syncthreads();

    const int   bsel = bsel_sh[half];
    const int   krem = krem_sh[half];
    const float hi  = (bsel == NBINS - 1) ? __builtin_inff() : (float)(bsel + 1);
    const float mid = (float)bsel + 0.5f;

    float s = 0.f;
#pragma unroll
    for (int j = 0; j < 8; ++j) {
        float a = fabsf(av[j]);
        s += (a >= hi) ? a : 0.f;
    }

    float dot = dot2.x + dot2.y;
    float nrm = nrm2.x + nrm2.y;
#pragma unroll
    for (int o = 32; o > 0; o >>= 1) {
        dot += __shfl_down(dot, o, 64);
        nrm += __shfl_down(nrm, o, 64);
        s   += __shfl_down(s,   o, 64);
    }
    const int wave = t >> 6;
    if ((t & 63) == 0) {
        red[half][wave][0] = dot;
        red[half][wave][1] = nrm;
        red[half][wave][2] = s;
    }
    __syncthreads();
    dot = red[half][0][0] + red[half][1][0] + red[half][2][0] + red[half][3][0];
    nrm = red[half][0][1] + red[half][1][1] + red[half][2][1] + red[half][3][1];
    s   = red[half][0][2] + red[half][1][2] + red[half][2][2] + red[half][3][2];

    // true topk_sum = (s + krem*mid)/32 ; mean = /KSEL
    const float topk_mean = (s + (float)krem * mid) * (1.0f / (32.0f * KSEL));
    const float cosv = dot * __builtin_amdgcn_rsqf(fmaxf(nrm, 1e-24f));
    const float yt = sigma * topk_mean;
    const float et = __expf(-2.0f * yt);
    const float th = (1.0f - et) * __builtin_amdgcn_rcpf(1.0f + et);  // tanh
    const float gate = __expf(-tau * cosv) * fmaf(w, th, 1.0f);

    f4 oa, ob;
    oa.lo = g[0] * gate;   // pk_mul
    oa.hi = g[1] * gate;
    ob.lo = g[2] * gate;
    ob.hi = g[3] * gate;
    f4* outr = (f4*)(out + rowoff);
    __builtin_nontemporal_store(oa, outr + t);
    __builtin_nontemporal_store(ob, outr + t + NT);
}

extern "C" void kernel_launch(void* const* d_in, const int* in_sizes, int n_in,
                              void* d_out, int out_size, void* d_ws, size_t ws_size,
                              hipStream_t stream) {
    (void)n_in; (void)out_size; (void)ws_size;
    const float* x         = (const float*)d_in[0];
    const float* ema_mean  = (const float*)d_in[1];
    const float* ema_sq    = (const float*)d_in[2];
    const float* ema_out   = (const float*)d_in[3];
    const float* log_tau   = (const float*)d_in[4];
    const float* log_sigma = (const float*)d_in[5];
    const float* log_w     = (const float*)d_in[6];
    float* out = (float*)d_out;
    float* ws  = (float*)d_ws;

    prep_kernel<<<1, NT, 0, stream>>>(ema_mean, ema_sq, ema_out,
                                      log_tau, log_sigma, log_w, ws);
    const int rows = in_sizes[0] / D;   // B*T = 16384
    row_kernel<<<rows / 2, 512, 0, stream>>>(x, ws, out);
}

// Round 5
// 50.286 us; speedup vs baseline: 1.0613x; 1.0613x over previous
//
#include <hip/hip_runtime.h>
#include <math.h>

#define D      2048
#define KSEL   256
#define NT     256          // threads per block; NT*8 == D
#define NBINS  256
#define ROWS   2            // rows per block, processed serially

typedef float f4 __attribute__((ext_vector_type(4)));
typedef int   i4 __attribute__((ext_vector_type(4)));

// tanh-form GELU: x * sigmoid(1.5957691*x + 0.0713548*x^3)
__device__ __forceinline__ float fast_gelu(float x) {
    float x2 = x * x;
    float t  = fmaf(x2, -0.0713548162f, -1.5957691216f);
    float e  = __expf(x * t);
    return x * __builtin_amdgcn_rcpf(1.0f + e);
}

// ws layout: [0:D) a = 32/std ; [D:2D) b = -32*mean/std ;
//            [2D:3D) u = ema_out/(||ema_out||+1e-8) ; [3D:3D+3) tau,sigma,w
__global__ __launch_bounds__(NT) void prep_kernel(
    const float* __restrict__ ema_mean,
    const float* __restrict__ ema_sq,
    const float* __restrict__ ema_out,
    const float* __restrict__ p_log_tau,
    const float* __restrict__ p_log_sigma,
    const float* __restrict__ p_log_w,
    float* __restrict__ ws)
{
    __shared__ float red[4];
    const int tid = threadIdx.x;
    float ss = 0.f;
#pragma unroll
    for (int k = 0; k < D / NT; ++k) {
        int i = tid + k * NT;
        float m = ema_mean[i];
        float v = fmaxf(fmaf(-m, m, ema_sq[i]), 1e-6f);
        float inv = 32.0f * __builtin_amdgcn_rsqf(v);   // 32/std
        ws[i]     = inv;
        ws[D + i] = -m * inv;
        float e = ema_out[i];
        ss = fmaf(e, e, ss);
    }
#pragma unroll
    for (int o = 32; o > 0; o >>= 1) ss += __shfl_down(ss, o, 64);
    if ((tid & 63) == 0) red[tid >> 6] = ss;
    __syncthreads();
    float inv_nrm = 1.0f / (sqrtf(red[0] + red[1] + red[2] + red[3]) + 1e-8f);
#pragma unroll
    for (int k = 0; k < D / NT; ++k) {
        int i = tid + k * NT;
        ws[2 * D + i] = ema_out[i] * inv_nrm;
    }
    if (tid == 0) {
        ws[3 * D + 0] = __expf(p_log_tau[0]);
        ws[3 * D + 1] = __logf(1.0f + __expf(p_log_sigma[0])) + 0.01f;
        ws[3 * D + 2] = __logf(1.0f + __expf(p_log_w[0]));
    }
}

__global__ __launch_bounds__(NT) void row_kernel(
    const float* __restrict__ x,
    const float* __restrict__ ws,
    float* __restrict__ out)
{
    __shared__ int   hist[NBINS];
    __shared__ float red[4][3];
    __shared__ int   bsel_sh, krem_sh;

    const int t    = threadIdx.x;
    const int wave = t >> 6;
    const int lane = t & 63;

    // row-invariant state: registers for the whole block lifetime
    const float tau   = ws[3 * D + 0];
    const float sigma = ws[3 * D + 1];
    const float w     = ws[3 * D + 2];

    f4 aa = ((const f4*)ws)[t];
    f4 ab = ((const f4*)ws)[t + NT];
    f4 ba = ((const f4*)(ws + D))[t];
    f4 bb = ((const f4*)(ws + D))[t + NT];
    f4 ua = ((const f4*)(ws + 2 * D))[t];
    f4 ub = ((const f4*)(ws + 2 * D))[t + NT];
    const float a_[8] = {aa.x,aa.y,aa.z,aa.w, ab.x,ab.y,ab.z,ab.w};
    const float b_[8] = {ba.x,ba.y,ba.z,ba.w, bb.x,bb.y,bb.z,bb.w};
    const float u_[8] = {ua.x,ua.y,ua.z,ua.w, ub.x,ub.y,ub.z,ub.w};

    const size_t row0 = (size_t)blockIdx.x * ROWS;
    f4 xa = ((const f4*)(x + row0 * D))[t];
    f4 xb = ((const f4*)(x + row0 * D))[t + NT];

    hist[t] = 0;
    __syncthreads();                       // B0: zeros visible

#pragma unroll
    for (int r = 0; r < ROWS; ++r) {
        const float xv[8] = {xa.x,xa.y,xa.z,xa.w, xb.x,xb.y,xb.z,xb.w};

        float g[8];
        float dot = 0.f, nrm = 0.f;
#pragma unroll
        for (int j = 0; j < 8; ++j) {
            float gg = fast_gelu(xv[j]);
            g[j] = gg;
            dot = fmaf(gg, u_[j], dot);
            nrm = fmaf(gg, gg, nrm);
        }

        // prefetch next row's x — latency hides under this row's epilogue
        if (r + 1 < ROWS) {
            const float* xn = x + (row0 + r + 1) * D;
            xa = ((const f4*)xn)[t];
            xb = ((const f4*)xn)[t + NT];
        }

        // histogram of 32*|z| (z recomputed: 1 fma, abs is a src modifier)
#pragma unroll
        for (int j = 0; j < 8; ++j) {
            float zz = fabsf(fmaf(xv[j], a_[j], b_[j]));
            int bin = (int)zz;
            bin = bin > NBINS - 1 ? NBINS - 1 : bin;
            atomicAdd(&hist[bin], 1);
        }
        __syncthreads();                   // B1: histogram complete

        // single-wave suffix scan over 256 bins (descending)
        if (wave == 0) {
            int base = (NBINS - 4) - 4 * lane;          // 252 - 4*lane
            i4 v = *(const i4*)&hist[base];
            // descending-order partial sums within lane
            int c0 = v.w;
            int c1 = c0 + v.z;
            int c2 = c1 + v.y;
            int c3 = c2 + v.x;
            int p = c3;
#pragma unroll
            for (int o = 1; o < 64; o <<= 1) {
                int q = __shfl_up(p, o, 64);
                if (lane >= o) p += q;
            }
            int excl = p - c3;             // # values in bins strictly above this lane's 4
            int s0 = excl,      i0 = excl + c0;
            int s1 = i0,        i1 = excl + c1;
            int s2 = i1,        i2 = excl + c2;
            int s3 = i2,        i3 = excl + c3;
            if (s0 < KSEL && i0 >= KSEL) { bsel_sh = base + 3; krem_sh = KSEL - s0; }
            if (s1 < KSEL && i1 >= KSEL) { bsel_sh = base + 2; krem_sh = KSEL - s1; }
            if (s2 < KSEL && i2 >= KSEL) { bsel_sh = base + 1; krem_sh = KSEL - s2; }
            if (s3 < KSEL && i3 >= KSEL) { bsel_sh = base;     krem_sh = KSEL - s3; }
        }
        __syncthreads();                   // B2: bsel/krem visible

        const int   bsel = bsel_sh;
        const int   krem = krem_sh;
        const float hi  = (bsel == NBINS - 1) ? __builtin_inff() : (float)(bsel + 1);
        const float mid = (float)bsel + 0.5f;

        float s = 0.f;
#pragma unroll
        for (int j = 0; j < 8; ++j) {
            float zz = fabsf(fmaf(xv[j], a_[j], b_[j]));
            s += (zz >= hi) ? zz : 0.f;
        }

#pragma unroll
        for (int o = 32; o > 0; o >>= 1) {
            dot += __shfl_down(dot, o, 64);
            nrm += __shfl_down(nrm, o, 64);
            s   += __shfl_down(s,   o, 64);
        }
        if (lane == 0) {
            red[wave][0] = dot; red[wave][1] = nrm; red[wave][2] = s;
        }
        hist[t] = 0;                       // re-zero for next row (pre-B3)
        __syncthreads();                   // B3: red + zeros visible

        dot = red[0][0] + red[1][0] + red[2][0] + red[3][0];
        nrm = red[0][1] + red[1][1] + red[2][1] + red[3][1];
        s   = red[0][2] + red[1][2] + red[2][2] + red[3][2];

        // true topk_sum = (s + krem*mid)/32 ; mean = /KSEL
        const float topk_mean = (s + (float)krem * mid) * (1.0f / (32.0f * KSEL));
        const float cosv = dot * __builtin_amdgcn_rsqf(fmaxf(nrm, 1e-24f));
        const float yt = sigma * topk_mean;
        const float et = __expf(-2.0f * yt);
        const float th = (1.0f - et) * __builtin_amdgcn_rcpf(1.0f + et);  // tanh
        const float gate = __expf(-tau * cosv) * fmaf(w, th, 1.0f);

        f4 oa, ob;
        oa.x = g[0]*gate; oa.y = g[1]*gate; oa.z = g[2]*gate; oa.w = g[3]*gate;
        ob.x = g[4]*gate; ob.y = g[5]*gate; ob.z = g[6]*gate; ob.w = g[7]*gate;
        f4* outr = (f4*)(out + (row0 + r) * D);
        __builtin_nontemporal_store(oa, outr + t);
        __builtin_nontemporal_store(ob, outr + t + NT);
    }
}

extern "C" void kernel_launch(void* const* d_in, const int* in_sizes, int n_in,
                              void* d_out, int out_size, void* d_ws, size_t ws_size,
                              hipStream_t stream) {
    (void)n_in; (void)out_size; (void)ws_size;
    const float* x         = (const float*)d_in[0];
    const float* ema_mean  = (const float*)d_in[1];
    const float* ema_sq    = (const float*)d_in[2];
    const float* ema_out   = (const float*)d_in[3];
    const float* log_tau   = (const float*)d_in[4];
    const float* log_sigma = (const float*)d_in[5];
    const float* log_w     = (const float*)d_in[6];
    float* out = (float*)d_out;
    float* ws  = (float*)d_ws;

    prep_kernel<<<1, NT, 0, stream>>>(ema_mean, ema_sq, ema_out,
                                      log_tau, log_sigma, log_w, ws);
    const int rows = in_sizes[0] / D;   // B*T = 16384
    row_kernel<<<rows / ROWS, NT, 0, stream>>>(x, ws, out);
}

// Round 6
// 50.205 us; speedup vs baseline: 1.0630x; 1.0016x over previous
//
#include <hip/hip_runtime.h>
#include <math.h>

#define D      2048
#define KSEL   256
#define NT     256          // threads per block; NT*8 == D
#define NBINS  512          // bins of width 1/64 over |z| in [0,8)
#define ROWS   2            // rows per block, processed serially

typedef float f4 __attribute__((ext_vector_type(4)));
typedef int   i4 __attribute__((ext_vector_type(4)));

// tanh-form GELU: x * sigmoid(1.5957691*x + 0.0713548*x^3)
__device__ __forceinline__ float fast_gelu(float x) {
    float x2 = x * x;
    float t  = fmaf(x2, -0.0713548162f, -1.5957691216f);
    float e  = __expf(x * t);
    return x * __builtin_amdgcn_rcpf(1.0f + e);
}

// ---- DPP cross-lane (VALU pipe, no LDS) ----
template<int CTRL, int RMASK>
__device__ __forceinline__ float dpp_mov_f(float v) {
    int r = __builtin_amdgcn_update_dpp(0, __builtin_bit_cast(int, v),
                                        CTRL, RMASK, 0xf, true);
    return __builtin_bit_cast(float, r);
}
template<int CTRL, int RMASK>
__device__ __forceinline__ int dpp_mov_i(int v) {
    return __builtin_amdgcn_update_dpp(0, v, CTRL, RMASK, 0xf, true);
}
// inclusive prefix-sum across 64 lanes; lane 63 ends with the wave total
__device__ __forceinline__ float wave_scan_f(float x) {
    x += dpp_mov_f<0x111, 0xf>(x);   // row_shr:1
    x += dpp_mov_f<0x112, 0xf>(x);   // row_shr:2
    x += dpp_mov_f<0x114, 0xf>(x);   // row_shr:4
    x += dpp_mov_f<0x118, 0xf>(x);   // row_shr:8
    x += dpp_mov_f<0x142, 0xa>(x);   // row_bcast:15 -> rows 1,3
    x += dpp_mov_f<0x143, 0xc>(x);   // row_bcast:31 -> rows 2,3
    return x;
}
__device__ __forceinline__ int wave_scan_i(int x) {
    x += dpp_mov_i<0x111, 0xf>(x);
    x += dpp_mov_i<0x112, 0xf>(x);
    x += dpp_mov_i<0x114, 0xf>(x);
    x += dpp_mov_i<0x118, 0xf>(x);
    x += dpp_mov_i<0x142, 0xa>(x);
    x += dpp_mov_i<0x143, 0xc>(x);
    return x;
}

// ws layout: [0:D) a = 64/std ; [D:2D) b = -64*mean/std ;
//            [2D:3D) u = ema_out/(||ema_out||+1e-8) ; [3D:3D+3) tau,sigma,w
__global__ __launch_bounds__(NT) void prep_kernel(
    const float* __restrict__ ema_mean,
    const float* __restrict__ ema_sq,
    const float* __restrict__ ema_out,
    const float* __restrict__ p_log_tau,
    const float* __restrict__ p_log_sigma,
    const float* __restrict__ p_log_w,
    float* __restrict__ ws)
{
    __shared__ float red[4];
    const int tid = threadIdx.x;
    float ss = 0.f;
#pragma unroll
    for (int k = 0; k < D / NT; ++k) {
        int i = tid + k * NT;
        float m = ema_mean[i];
        float v = fmaxf(fmaf(-m, m, ema_sq[i]), 1e-6f);
        float inv = 64.0f * __builtin_amdgcn_rsqf(v);   // 64/std
        ws[i]     = inv;
        ws[D + i] = -m * inv;
        float e = ema_out[i];
        ss = fmaf(e, e, ss);
    }
    ss = wave_scan_f(ss);
    if ((tid & 63) == 63) red[tid >> 6] = ss;
    __syncthreads();
    float inv_nrm = 1.0f / (sqrtf(red[0] + red[1] + red[2] + red[3]) + 1e-8f);
#pragma unroll
    for (int k = 0; k < D / NT; ++k) {
        int i = tid + k * NT;
        ws[2 * D + i] = ema_out[i] * inv_nrm;
    }
    if (tid == 0) {
        ws[3 * D + 0] = __expf(p_log_tau[0]);
        ws[3 * D + 1] = __logf(1.0f + __expf(p_log_sigma[0])) + 0.01f;
        ws[3 * D + 2] = __logf(1.0f + __expf(p_log_w[0]));
    }
}

__global__ __launch_bounds__(NT) void row_kernel(
    const float* __restrict__ x,
    const float* __restrict__ ws,
    float* __restrict__ out)
{
    __shared__ int   hist[NBINS];    // REVERSED: hist[NBINS-1-bin]
    __shared__ float red[4][3];
    __shared__ int   bsel_sh, krem_sh;

    const int t    = threadIdx.x;
    const int wave = t >> 6;
    const int lane = t & 63;

    const float tau   = ws[3 * D + 0];
    const float sigma = ws[3 * D + 1];
    const float w     = ws[3 * D + 2];

    f4 aa = ((const f4*)ws)[t];
    f4 ab = ((const f4*)ws)[t + NT];
    f4 ba = ((const f4*)(ws + D))[t];
    f4 bb = ((const f4*)(ws + D))[t + NT];
    f4 ua = ((const f4*)(ws + 2 * D))[t];
    f4 ub = ((const f4*)(ws + 2 * D))[t + NT];
    const float a_[8] = {aa.x,aa.y,aa.z,aa.w, ab.x,ab.y,ab.z,ab.w};
    const float b_[8] = {ba.x,ba.y,ba.z,ba.w, bb.x,bb.y,bb.z,bb.w};
    const float u_[8] = {ua.x,ua.y,ua.z,ua.w, ub.x,ub.y,ub.z,ub.w};

    const size_t row0 = (size_t)blockIdx.x * ROWS;
    f4 xa = ((const f4*)(x + row0 * D))[t];
    f4 xb = ((const f4*)(x + row0 * D))[t + NT];

    hist[t] = 0;
    hist[t + NT] = 0;
    __syncthreads();                       // B0: zeros visible

#pragma unroll
    for (int r = 0; r < ROWS; ++r) {
        const float xv[8] = {xa.x,xa.y,xa.z,xa.w, xb.x,xb.y,xb.z,xb.w};

        float g[8], av[8];
        float dot = 0.f, nrm = 0.f;
#pragma unroll
        for (int j = 0; j < 8; ++j) {
            float gg = fast_gelu(xv[j]);
            g[j] = gg;
            av[j] = fabsf(fmaf(xv[j], a_[j], b_[j]));   // 64*|z|
            dot = fmaf(gg, u_[j], dot);
            nrm = fmaf(gg, gg, nrm);
        }

        // prefetch next row's x — latency hides under this row's epilogue
        if (r + 1 < ROWS) {
            const float* xn = x + (row0 + r + 1) * D;
            xa = ((const f4*)xn)[t];
            xb = ((const f4*)xn)[t + NT];
        }

        // reversed-bin histogram
#pragma unroll
        for (int j = 0; j < 8; ++j) {
            int bin = (int)av[j];
            bin = bin > NBINS - 1 ? NBINS - 1 : bin;
            atomicAdd(&hist[(NBINS - 1) - bin], 1);
        }
        __syncthreads();                   // B1: histogram complete

        // wave0: prefix scan over 512 reversed bins (8 bins/lane) + crossing
        if (wave == 0) {
            i4 va = *(const i4*)&hist[8 * lane];
            i4 vb = *(const i4*)&hist[8 * lane + 4];
            int c0 = va.x;
            int c1 = c0 + va.y;
            int c2 = c1 + va.z;
            int c3 = c2 + va.w;
            int c4 = c3 + vb.x;
            int c5 = c4 + vb.y;
            int c6 = c5 + vb.z;
            int c7 = c6 + vb.w;
            int incl = wave_scan_i(c7);
            int excl = incl - c7;          // total of all lanes before this one
            int pre[8] = {0, c0, c1, c2, c3, c4, c5, c6};
            int cum[8] = {c0, c1, c2, c3, c4, c5, c6, c7};
#pragma unroll
            for (int k = 0; k < 8; ++k) {
                int s = excl + pre[k];
                int e = excl + cum[k];
                if (s < KSEL && e >= KSEL) {
                    bsel_sh = (NBINS - 1) - (8 * lane + k);
                    krem_sh = KSEL - s;
                }
            }
        }
        __syncthreads();                   // B2: bsel/krem visible

        const int   bsel = bsel_sh;
        const int   krem = krem_sh;
        const float hi  = (bsel == NBINS - 1) ? __builtin_inff() : (float)(bsel + 1);
        const float mid = (float)bsel + 0.5f;

        float s = 0.f;
#pragma unroll
        for (int j = 0; j < 8; ++j) {
            s += (av[j] >= hi) ? av[j] : 0.f;
        }

        // per-wave reduce via DPP (lane 63 holds totals)
        dot = wave_scan_f(dot);
        nrm = wave_scan_f(nrm);
        s   = wave_scan_f(s);
        if (lane == 63) {
            red[wave][0] = dot; red[wave][1] = nrm; red[wave][2] = s;
        }
        hist[t] = 0;                       // re-zero for next row (pre-B3)
        hist[t + NT] = 0;
        __syncthreads();                   // B3: red + zeros visible

        dot = red[0][0] + red[1][0] + red[2][0] + red[3][0];
        nrm = red[0][1] + red[1][1] + red[2][1] + red[3][1];
        s   = red[0][2] + red[1][2] + red[2][2] + red[3][2];

        // true topk_sum = (s + krem*mid)/64 ; mean = /KSEL
        const float topk_mean = (s + (float)krem * mid) * (1.0f / (64.0f * KSEL));
        const float cosv = dot * __builtin_amdgcn_rsqf(fmaxf(nrm, 1e-24f));
        const float yt = sigma * topk_mean;
        const float et = __expf(-2.0f * yt);
        const float th = (1.0f - et) * __builtin_amdgcn_rcpf(1.0f + et);  // tanh
        const float gate = __expf(-tau * cosv) * fmaf(w, th, 1.0f);

        f4 oa, ob;
        oa.x = g[0]*gate; oa.y = g[1]*gate; oa.z = g[2]*gate; oa.w = g[3]*gate;
        ob.x = g[4]*gate; ob.y = g[5]*gate; ob.z = g[6]*gate; ob.w = g[7]*gate;
        f4* outr = (f4*)(out + (row0 + r) * D);
        __builtin_nontemporal_store(oa, outr + t);
        __builtin_nontemporal_store(ob, outr + t + NT);
    }
}

extern "C" void kernel_launch(void* const* d_in, const int* in_sizes, int n_in,
                              void* d_out, int out_size, void* d_ws, size_t ws_size,
                              hipStream_t stream) {
    (void)n_in; (void)out_size; (void)ws_size;
    const float* x         = (const float*)d_in[0];
    const float* ema_mean  = (const float*)d_in[1];
    const float* ema_sq    = (const float*)d_in[2];
    const float* ema_out   = (const float*)d_in[3];
    const float* log_tau   = (const float*)d_in[4];
    const float* log_sigma = (const float*)d_in[5];
    const float* log_w     = (const float*)d_in[6];
    float* out = (float*)d_out;
    float* ws  = (float*)d_ws;

    prep_kernel<<<1, NT, 0, stream>>>(ema_mean, ema_sq, ema_out,
                                      log_tau, log_sigma, log_w, ws);
    const int rows = in_sizes[0] / D;   // B*T = 16384
    row_kernel<<<rows / ROWS, NT, 0, stream>>>(x, ws, out);
}